// Round 1
// baseline (600.201 us; speedup 1.0000x reference)
//
#include <hip/hip_runtime.h>
#include <cstdint>

// ---------------------------------------------------------------------------
// NVFP4 fake-quant GEMM: out = fq4(x) @ fq4(w)^T + bias
// fq4: per-16-group (along K) scale = e4m3_rt(amax/6), values on e2m1 grid.
// dq = q*scale is EXACT in bf16 (<=6 significant bits), so we quantize into
// bf16 buffers in d_ws and run a bf16-MFMA GEMM (m97 structure, ref-checked
// fragment layouts from the CDNA4 guide).
// ---------------------------------------------------------------------------

typedef __attribute__((ext_vector_type(8))) __bf16 bf16x8;
typedef __attribute__((ext_vector_type(4))) float f32x4;

typedef __attribute__((address_space(1))) void gvoid;
typedef __attribute__((address_space(3))) void lvoid;

// Exact fp8 e4m3fn round-trip for x >= 0, x well below 448.
// Normal range (x >= 2^-6): RNE to 3 mantissa bits via integer trick.
// Subnormal range (x < 2^-6): grid lsb is 2^-9 -> rintf (RNE) on x*512.
__device__ __forceinline__ float fp8_e4m3_rt(float x) {
    if (x < 0.015625f) {
        return __builtin_rintf(x * 512.0f) * (1.0f / 512.0f);
    }
    unsigned u = __float_as_uint(x);
    unsigned lsb = (u >> 20) & 1u;
    u = (u + 0x7FFFFu + lsb) & ~0xFFFFFu;
    return __uint_as_float(u);
}

// Reference's e2m1 rounding: clip(|v|,0,6), threshold chain, re-sign.
__device__ __forceinline__ float round_e2m1(float v) {
    float a = fabsf(v);
    a = fminf(a, 6.0f);
    float q = a < 0.25f ? 0.0f :
              a < 0.75f ? 0.5f :
              a < 1.25f ? 1.0f :
              a < 1.75f ? 1.5f :
              a < 2.5f  ? 2.0f :
              a < 3.5f  ? 3.0f :
              a < 5.0f  ? 4.0f : 6.0f;
    return copysignf(q, v);
}

// One thread = 4 consecutive floats; group of 16 = 4 consecutive lanes.
// Fully coalesced float4 loads, amax via 2x shfl_xor within the lane quad.
__global__ __launch_bounds__(256) void quant_fp4(const float* __restrict__ in,
                                                 uint16_t* __restrict__ out,
                                                 int nquads) {
    int i = blockIdx.x * 256 + threadIdx.x;
    if (i >= nquads) return;
    float4 v = ((const float4*)in)[i];
    float a = fmaxf(fmaxf(fabsf(v.x), fabsf(v.y)), fmaxf(fabsf(v.z), fabsf(v.w)));
    a = fmaxf(a, __shfl_xor(a, 1));
    a = fmaxf(a, __shfl_xor(a, 2));
    float scale = fp8_e4m3_rt(a / 6.0f);
    float safe = scale > 0.0f ? scale : 1.0f;
    float vals[4] = {v.x, v.y, v.z, v.w};
    unsigned r[4];
    #pragma unroll
    for (int e = 0; e < 4; ++e) {
        float q = round_e2m1(vals[e] / safe);           // exact fp32 div, like ref
        float dq = scale > 0.0f ? q * scale : 0.0f;     // exact product
        r[e] = __float_as_uint(dq) >> 16;               // exact bf16 (low bits 0)
    }
    uint2 o;
    o.x = r[0] | (r[1] << 16);
    o.y = r[2] | (r[3] << 16);
    ((uint2*)out)[i] = o;
}

// ---------------------------------------------------------------------------
// bf16 GEMM, C[M,N] = A[M,K] * B[N,K]^T + bias. m97 structure:
// 128x128 tile, BK=32, 256 threads = 4 waves (2x2 of 64x64), 4x4 accs of
// v_mfma_f32_16x16x32_bf16, staging via global_load_lds width=16.
// ---------------------------------------------------------------------------
#define BM 128
#define BN 128
#define BK 32

__global__ __launch_bounds__(256)
void gemm_w4a4(const uint16_t* __restrict__ Aq, const uint16_t* __restrict__ Bq,
               const float* __restrict__ bias, float* __restrict__ C,
               int M, int N, int K) {
    __shared__ __align__(16) uint16_t lA[BM * BK];
    __shared__ __align__(16) uint16_t lB[BN * BK];

    const int t    = threadIdx.x;
    const int wave = t >> 6;
    const int lane = t & 63;
    const int wm   = (wave >> 1) * 64;   // wave's m offset in tile
    const int wn   = (wave & 1) * 64;    // wave's n offset in tile
    const int mBase = blockIdx.y * BM;
    const int nBase = blockIdx.x * BN;
    const int lrow = lane & 15;          // fragment row (m for A, n for B)
    const int kq   = (lane >> 4) * 8;    // fragment k offset

    f32x4 acc[4][4] = {};

    for (int k0 = 0; k0 < K; k0 += BK) {
        // Stage A/B tiles: 8192 B each = 512 chunks of 16 B; chunk c = it*256+t.
        // LDS dest is wave-uniform base + lane*16 (m104 caveat) -> contiguous
        // row-major [128][32] layout, chunk c -> row c>>2, k (c&3)*8.
        #pragma unroll
        for (int it = 0; it < 2; ++it) {
            const int c   = it * 256 + t;
            const int row = c >> 2;
            const int kc  = (c & 3) * 8;
            const uint16_t* gA = Aq + (size_t)(mBase + row) * K + (k0 + kc);
            const uint16_t* gB = Bq + (size_t)(nBase + row) * K + (k0 + kc);
            const int ldsOff = (it * 256 + wave * 64) * 8;  // ushort index
            __builtin_amdgcn_global_load_lds((gvoid*)gA, (lvoid*)&lA[ldsOff], 16, 0, 0);
            __builtin_amdgcn_global_load_lds((gvoid*)gB, (lvoid*)&lB[ldsOff], 16, 0, 0);
        }
        __syncthreads();

        // Fragments: lane holds row (lane&15), k = (lane>>4)*8 + j  (ds_read_b128)
        bf16x8 af[4], bfr[4];
        #pragma unroll
        for (int i = 0; i < 4; ++i)
            af[i] = *(const bf16x8*)&lA[(wm + i * 16 + lrow) * BK + kq];
        #pragma unroll
        for (int j = 0; j < 4; ++j)
            bfr[j] = *(const bf16x8*)&lB[(wn + j * 16 + lrow) * BK + kq];

        #pragma unroll
        for (int i = 0; i < 4; ++i)
            #pragma unroll
            for (int j = 0; j < 4; ++j)
                acc[i][j] = __builtin_amdgcn_mfma_f32_16x16x32_bf16(
                    af[i], bfr[j], acc[i][j], 0, 0, 0);
        __syncthreads();
    }

    // Epilogue: C/D layout col = lane&15, row = (lane>>4)*4 + reg (m89/m91).
    const int rq = (lane >> 4) * 4;
    #pragma unroll
    for (int j = 0; j < 4; ++j) {
        const int col = nBase + wn + j * 16 + lrow;
        const float bj = bias[col];
        #pragma unroll
        for (int i = 0; i < 4; ++i) {
            const int row0 = mBase + wm + i * 16 + rq;
            #pragma unroll
            for (int r = 0; r < 4; ++r)
                C[(size_t)(row0 + r) * N + col] = acc[i][j][r] + bj;
        }
    }
}

extern "C" void kernel_launch(void* const* d_in, const int* in_sizes, int n_in,
                              void* d_out, int out_size, void* d_ws, size_t ws_size,
                              hipStream_t stream) {
    const float* x    = (const float*)d_in[0];
    const float* w    = (const float*)d_in[1];
    const float* bias = (const float*)d_in[2];
    float* out = (float*)d_out;

    const int N = in_sizes[2];            // bias length
    const int K = in_sizes[1] / N;        // weight is [N,K]
    const int M = in_sizes[0] / K;        // x is [M,K]

    uint16_t* xq = (uint16_t*)d_ws;                 // M*K bf16 = 64 MiB
    uint16_t* wq = xq + (size_t)M * K;              // N*K bf16 = 32 MiB

    const int xquads = (M * K) / 4;
    const int wquads = (N * K) / 4;
    quant_fp4<<<(xquads + 255) / 256, 256, 0, stream>>>(x, xq, xquads);
    quant_fp4<<<(wquads + 255) / 256, 256, 0, stream>>>(w, wq, wquads);

    dim3 grid(N / BN, M / BM);
    gemm_w4a4<<<grid, 256, 0, stream>>>(xq, wq, bias, out, M, N, K);
}